// Round 9
// baseline (141.836 us; speedup 1.0000x reference)
//
#include <hip/hip_runtime.h>
#include <hip/hip_bf16.h>
#include <math.h>

#define SEQ    2048
#define DH     64
#define EMB    512
#define INDIM  512
#define NHEADS 8
#define BATCH  4
#define MTOT   (BATCH * SEQ)   // 8192

typedef __attribute__((ext_vector_type(8))) short bf16x8;   // 8 bf16 = 4 VGPR
typedef __attribute__((ext_vector_type(4))) float f32x4;

__device__ __forceinline__ ushort f2bf(float x) {
  union { float f; unsigned u; } v; v.f = x;
  unsigned r = v.u + 0x7FFFu + ((v.u >> 16) & 1u);   // RNE
  return (ushort)(r >> 16);
}

// packed f32x2 -> bf16x2 (single HW op)
__device__ __forceinline__ unsigned cvt_pk_bf16(float lo, float hi) {
  unsigned r;
  asm("v_cvt_pk_bf16_f32 %0, %1, %2" : "=v"(r) : "v"(lo), "v"(hi));
  return r;
}

// raw v_exp_f32 (exp2); args bounded (static-max softmax)
__device__ __forceinline__ float fast_exp2(float x) {
  float r;
  asm("v_exp_f32 %0, %1" : "=v"(r) : "v"(x));
  return r;
}

// v_permlane32_swap_b32: x.h1 <-> y.h0.  After: x = [x.h0, y.h0], y = [x.h1, y.h1]
__device__ __forceinline__ void permswap32(unsigned &x, unsigned &y) {
  asm("v_permlane32_swap_b32 %0, %1" : "+v"(x), "+v"(y));
}

// ---------------------------------------------------------------------------
// f32 -> bf16 conversion, 8 elems/thread
// ---------------------------------------------------------------------------
__global__ __launch_bounds__(256) void conv_bf16(const float* __restrict__ src,
                                                 ushort* __restrict__ dst, int n8) {
  const int i = blockIdx.x * 256 + threadIdx.x;
  if (i >= n8) return;
  const float4 a = ((const float4*)src)[i * 2];
  const float4 b = ((const float4*)src)[i * 2 + 1];
  uint4 o;
  o.x = cvt_pk_bf16(a.x, a.y);
  o.y = cvt_pk_bf16(a.z, a.w);
  o.z = cvt_pk_bf16(b.x, b.y);
  o.w = cvt_pk_bf16(b.z, b.w);
  ((uint4*)dst)[i] = o;
}

// 4 weight matrices in one launch (blockIdx.y selects)
__global__ __launch_bounds__(256) void conv_bf16_w4(
    const float* __restrict__ w0, const float* __restrict__ w1,
    const float* __restrict__ w2, const float* __restrict__ w3,
    ushort* __restrict__ dst, int n8per) {
  const int i = blockIdx.x * 256 + threadIdx.x;
  if (i >= n8per) return;
  const float* src = (blockIdx.y == 0) ? w0 : (blockIdx.y == 1) ? w1
                   : (blockIdx.y == 2) ? w2 : w3;
  ushort* d = dst + (size_t)blockIdx.y * n8per * 8;
  const float4 a = ((const float4*)src)[i * 2];
  const float4 b = ((const float4*)src)[i * 2 + 1];
  uint4 o;
  o.x = cvt_pk_bf16(a.x, a.y);
  o.y = cvt_pk_bf16(a.z, a.w);
  o.z = cvt_pk_bf16(b.x, b.y);
  o.w = cvt_pk_bf16(b.z, b.w);
  ((uint4*)d)[i] = o;
}

// ---------------------------------------------------------------------------
// MFMA GEMM, m97 structure: 128x128 tile, BK=32, 4 waves, 4x4 16x16 frags/wave,
// global_load_lds width 16.
// MODE 0: fused QKV (N=1536). which=bn>>9: 0->Q (pre-scaled by 0.125*log2e),
//         1->K bf16 [B,H,N,Dh]; 2->V^T bf16 [B,H,Dh,N] via LDS transpose.
// MODE 1: out-projection, f32 out [M][EMB] + bias.
// ---------------------------------------------------------------------------
template <int MODE>
__global__ __launch_bounds__(256) void mfma_gemm(
    const ushort* __restrict__ A, const ushort* __restrict__ W,
    const float* __restrict__ b0, const float* __restrict__ b1,
    const float* __restrict__ b2,
    ushort* __restrict__ outQ, ushort* __restrict__ outK,
    ushort* __restrict__ outVT, float* __restrict__ outF) {
  __shared__ __align__(16) char smem[MODE == 0 ? 35840 : 16384];
  ushort* As = (ushort*)smem;            // [128][32] bf16 = 8 KB
  ushort* Bs = (ushort*)(smem + 8192);   // [128][32] bf16 = 8 KB
  ushort* Tl = (ushort*)smem;            // epilogue transpose [128][140]

  const int bm = blockIdx.x * 128;
  const int bn = blockIdx.y * 128;
  const int tid = threadIdx.x;
  const int wave = tid >> 6, lane = tid & 63;
  const int g = lane >> 4, ln = lane & 15;
  const int wr = wave >> 1, wc = wave & 1;

  f32x4 acc[4][4];
#pragma unroll
  for (int m = 0; m < 4; ++m)
#pragma unroll
    for (int n = 0; n < 4; ++n) acc[m][n] = (f32x4){0.f, 0.f, 0.f, 0.f};

  const size_t a_base = (size_t)(bm + wave * 16 + (lane >> 2)) * INDIM + (lane & 3) * 8;
  const size_t b_base = (size_t)(bn + wave * 16 + (lane >> 2)) * INDIM + (lane & 3) * 8;
  ushort* ldsA0 = As + wave * 512;
  ushort* ldsA1 = As + 2048 + wave * 512;
  ushort* ldsB0 = Bs + wave * 512;
  ushort* ldsB1 = Bs + 2048 + wave * 512;

  for (int k0 = 0; k0 < INDIM; k0 += 32) {
    __syncthreads();
    __builtin_amdgcn_global_load_lds(
        (const __attribute__((address_space(1))) void*)(A + a_base + k0),
        (__attribute__((address_space(3))) void*)ldsA0, 16, 0, 0);
    __builtin_amdgcn_global_load_lds(
        (const __attribute__((address_space(1))) void*)(A + a_base + 64 * INDIM + k0),
        (__attribute__((address_space(3))) void*)ldsA1, 16, 0, 0);
    __builtin_amdgcn_global_load_lds(
        (const __attribute__((address_space(1))) void*)(W + b_base + k0),
        (__attribute__((address_space(3))) void*)ldsB0, 16, 0, 0);
    __builtin_amdgcn_global_load_lds(
        (const __attribute__((address_space(1))) void*)(W + b_base + 64 * INDIM + k0),
        (__attribute__((address_space(3))) void*)ldsB1, 16, 0, 0);
    __syncthreads();

    bf16x8 af[4], bfv[4];
#pragma unroll
    for (int m = 0; m < 4; ++m)
      af[m] = *(const bf16x8*)&As[(64 * wr + 16 * m + ln) * 32 + 8 * g];
#pragma unroll
    for (int n = 0; n < 4; ++n)
      bfv[n] = *(const bf16x8*)&Bs[(64 * wc + 16 * n + ln) * 32 + 8 * g];
#pragma unroll
    for (int m = 0; m < 4; ++m)
#pragma unroll
      for (int n = 0; n < 4; ++n)
        acc[m][n] = __builtin_amdgcn_mfma_f32_16x16x32_bf16(af[m], bfv[n], acc[m][n], 0, 0, 0);
  }

  // ---- epilogue ----  C: row = bm+64wr+16m+4g+r, col e = bn+64wc+16n+ln
  if (MODE == 1) {
#pragma unroll
    for (int n = 0; n < 4; ++n) {
      const int e = bn + 64 * wc + 16 * n + ln;
      const float bv = b0[e];
#pragma unroll
      for (int m = 0; m < 4; ++m)
#pragma unroll
        for (int r = 0; r < 4; ++r) {
          const int row = bm + 64 * wr + 16 * m + 4 * g + r;
          outF[(size_t)row * EMB + e] = acc[m][n][r] + bv;
        }
    }
    return;
  }

  const int which = bn >> 9;
  const float* bias = (which == 0) ? b0 : (which == 1) ? b1 : b2;

  if (which < 2) {
    // Q gets the softmax scale folded in (log2 domain): 0.125 * log2(e)
    const float scl = (which == 0) ? 0.18033688f : 1.0f;
    ushort* dst = (which == 0) ? outQ : outK;
#pragma unroll
    for (int n = 0; n < 4; ++n) {
      const int e = (bn & 511) + 64 * wc + 16 * n + ln;
      const float bv = bias[e];
      const int h = e >> 6, d = e & 63;
#pragma unroll
      for (int m = 0; m < 4; ++m)
#pragma unroll
        for (int r = 0; r < 4; ++r) {
          const int row = bm + 64 * wr + 16 * m + 4 * g + r;
          const int b = row >> 11, nn = row & (SEQ - 1);
          dst[(((size_t)(b * NHEADS + h) * SEQ) + nn) * DH + d] =
              f2bf((acc[m][n][r] + bv) * scl);
        }
    }
  } else {
    // V: transpose through LDS, write V^T [B,H,Dh,N]
    __syncthreads();
#pragma unroll
    for (int n = 0; n < 4; ++n) {
      const int cl = 64 * wc + 16 * n + ln;
      const float bv = bias[(bn & 511) + cl];
#pragma unroll
      for (int m = 0; m < 4; ++m)
#pragma unroll
        for (int r = 0; r < 4; ++r) {
          const int rl = 64 * wr + 16 * m + 4 * g + r;
          Tl[cl * 140 + rl] = f2bf(acc[m][n][r] + bv);
        }
    }
    __syncthreads();
    const int c = tid >> 1;
    const int rh = (tid & 1) * 64;
    const int e = (bn & 511) + c;
    const int h = e >> 6, d = e & 63;
    const int b = bm >> 11;
    const int nn0 = (bm & (SEQ - 1)) + rh;
    ushort* drow = outVT + (((size_t)(b * NHEADS + h) * DH) + d) * SEQ + nn0;
#pragma unroll
    for (int j = 0; j < 8; ++j)
      *(bf16x8*)&drow[j * 8] = *(const bf16x8*)&Tl[c * 140 + rh + j * 8];
  }
}

// ---------------------------------------------------------------------------
// MFMA flash attention, LDS-lean + kv-split x4 for occupancy.
// 4 waves x 64 q-rows = 256 q/block; KV-step 64; each block covers a 512-row
// kv quarter (8 iters). Grid 1024 = 32bh x 8qx x 4quarter -> 4 blocks/CU
// = 4 waves/SIMD (VGPR 128, LDS 18KB). R7 was identical but 2 blocks/CU and
// measured 4900 cy/wave-iter vs ~1000 cy of issue work -> latency-bound;
// doubling resident waves fills the stall cycles.
// P never touches LDS (pi-permuted K staging + cvt_pk + 2 permlane32_swap
// produce PV A-fragments in-register). Static-max softmax (R4 bound).
// Partials combined via f32 atomicAdd (4 contributions; ~1ulp order noise).
// XCD swizzle: 4 bh per XCD -> K/V (2MB) L2-resident.
// ---------------------------------------------------------------------------
__global__ __launch_bounds__(256, 2) void attn_mfma(const ushort* __restrict__ Q,
                                                    const ushort* __restrict__ K,
                                                    const ushort* __restrict__ VT,
                                                    float* __restrict__ P,
                                                    float* __restrict__ L) {
  __shared__ __align__(16) ushort Kl[64 * 72];     // [kv(pi-permuted)][d] padded
  __shared__ __align__(16) ushort Vl[64 * 72];     // [d][kv] padded

  const int tid = threadIdx.x;
  const int wave = tid >> 6, lane = tid & 63;
  const int g = lane >> 4, ln = lane & 15;

  // XCD swizzle over 1024 wgs: swz = (orig%8)*128 + orig/8 (bijective; 4 bh/XCD)
  const int orig = blockIdx.x;
  const int swz = (orig & 7) * 128 + (orig >> 3);
  const int bh = swz >> 5;            // 0..31
  const int sub = swz & 31;
  const int qx = sub >> 2;            // 0..7
  const int quarter = sub & 3;        // kv quarter
  const int qbase = qx * 256 + wave * 64;
  const int kvbeg = quarter << 9;     // 0,512,1024,1536

  const ushort* Qb = Q + ((size_t)bh * SEQ + qbase) * DH;
  const ushort* Kb = K + (size_t)bh * SEQ * DH;
  const ushort* Vb = VT + (size_t)bh * DH * SEQ;

  // Q B-fragments for 4 q-groups (q = 16X + ln), two d-halves each
  bf16x8 qf[4][2];
#pragma unroll
  for (int X = 0; X < 4; ++X) {
    qf[X][0] = *(const bf16x8*)&Qb[(16 * X + ln) * DH + 8 * g];
    qf[X][1] = *(const bf16x8*)&Qb[(16 * X + ln) * DH + 32 + 8 * g];
  }

  f32x4 oacc[4][4];
#pragma unroll
  for (int X = 0; X < 4; ++X)
#pragma unroll
    for (int t = 0; t < 4; ++t) oacc[X][t] = (f32x4){0.f, 0.f, 0.f, 0.f};
  float denom[4] = {0.f, 0.f, 0.f, 0.f};

  const int skv = tid >> 3, sd = (tid & 7) * 8;   // K staging (rows skv, skv+32)
  const int dt = tid >> 2, kc = (tid & 3) * 8;    // V staging (d-row dt, cols kc, kc+32)
  // pi-permuted LDS rows for K: XOR 12 where bit2^bit3 (swaps rows 4-7 <-> 8-11)
  const int pr0 = skv ^ (((((skv >> 2) ^ (skv >> 3)) & 1)) * 12);
  const int s32 = skv + 32;
  const int pr1 = s32 ^ (((((s32 >> 2) ^ (s32 >> 3)) & 1)) * 12);

  const ushort* kp0 = Kb + (size_t)(kvbeg + skv) * DH + sd;
  const ushort* kp1 = kp0 + 32 * DH;
  const ushort* vp0 = Vb + (size_t)dt * SEQ + kvbeg + kc;
  const ushort* vp1 = vp0 + 32;

  bf16x8 k0v = *(const bf16x8*)kp0;
  bf16x8 k1v = *(const bf16x8*)kp1;
  bf16x8 v0v = *(const bf16x8*)vp0;
  bf16x8 v1v = *(const bf16x8*)vp1;

  for (int it = 0; it < 8; ++it) {
    __syncthreads();   // prev tile consumed
    *(bf16x8*)&Kl[pr0 * 72 + sd] = k0v;
    *(bf16x8*)&Kl[pr1 * 72 + sd] = k1v;
    *(bf16x8*)&Vl[dt * 72 + kc] = v0v;
    *(bf16x8*)&Vl[dt * 72 + 32 + kc] = v1v;

    // issue next tile's loads (fly during compute; raw barrier won't drain vmcnt)
    const size_t kadv = (it < 7) ? (size_t)(64 * DH) : 0;
    const int vadv = (it < 7) ? 64 : 0;
    kp0 += kadv; kp1 += kadv; vp0 += vadv; vp1 += vadv;
    k0v = *(const bf16x8*)kp0;
    k1v = *(const bf16x8*)kp1;
    v0v = *(const bf16x8*)vp0;
    v1v = *(const bf16x8*)vp1;

    asm volatile("s_waitcnt lgkmcnt(0)" ::: "memory");
    __builtin_amdgcn_s_barrier();

    // ---- shared fragments, read ONCE, reused by all 4 q-groups ----
    bf16x8 ka[4][2], vb[2][4];
#pragma unroll
    for (int t = 0; t < 4; ++t) {
      ka[t][0] = *(const bf16x8*)&Kl[(16 * t + ln) * 72 + 8 * g];
      ka[t][1] = *(const bf16x8*)&Kl[(16 * t + ln) * 72 + 32 + 8 * g];
    }
#pragma unroll
    for (int c = 0; c < 2; ++c)
#pragma unroll
      for (int t = 0; t < 4; ++t)
        vb[c][t] = *(const bf16x8*)&Vl[(16 * t + ln) * 72 + 32 * c + 8 * g];

#pragma unroll
    for (int X = 0; X < 4; ++X) {
      // ---- QK^T: sacc[t][r] = S(q=ln, kv = 16t + pi(4g+r)) ----
      f32x4 s0 = (f32x4){0.f, 0.f, 0.f, 0.f};
      f32x4 s1 = s0, s2 = s0, s3 = s0;
      __builtin_amdgcn_s_setprio(1);
      s0 = __builtin_amdgcn_mfma_f32_16x16x32_bf16(ka[0][0], qf[X][0], s0, 0, 0, 0);
      s1 = __builtin_amdgcn_mfma_f32_16x16x32_bf16(ka[1][0], qf[X][0], s1, 0, 0, 0);
      s2 = __builtin_amdgcn_mfma_f32_16x16x32_bf16(ka[2][0], qf[X][0], s2, 0, 0, 0);
      s3 = __builtin_amdgcn_mfma_f32_16x16x32_bf16(ka[3][0], qf[X][0], s3, 0, 0, 0);
      s0 = __builtin_amdgcn_mfma_f32_16x16x32_bf16(ka[0][1], qf[X][1], s0, 0, 0, 0);
      s1 = __builtin_amdgcn_mfma_f32_16x16x32_bf16(ka[1][1], qf[X][1], s1, 0, 0, 0);
      s2 = __builtin_amdgcn_mfma_f32_16x16x32_bf16(ka[2][1], qf[X][1], s2, 0, 0, 0);
      s3 = __builtin_amdgcn_mfma_f32_16x16x32_bf16(ka[3][1], qf[X][1], s3, 0, 0, 0);
      __builtin_amdgcn_s_setprio(0);

      // ---- P = exp2(S) (static max) ----
      float p0[4], p1[4], p2[4], p3[4];
#pragma unroll
      for (int r = 0; r < 4; ++r) {
        p0[r] = fast_exp2(s0[r]);
        p1[r] = fast_exp2(s1[r]);
        p2[r] = fast_exp2(s2[r]);
        p3[r] = fast_exp2(s3[r]);
      }

      // ---- denominator: in-lane 16-sum + cross-group reduce ----
      float ds = ((p0[0] + p0[1]) + (p0[2] + p0[3]))
               + ((p1[0] + p1[1]) + (p1[2] + p1[3]))
               + ((p2[0] + p2[1]) + (p2[2] + p2[3]))
               + ((p3[0] + p3[1]) + (p3[2] + p3[3]));
      ds += __shfl_xor(ds, 16);
      ds += __shfl_xor(ds, 32);
      denom[X] += ds;

      // ---- pack + permlane -> PV A-fragments (no LDS) ----
      unsigned a0 = cvt_pk_bf16(p0[0], p0[1]);
      unsigned a2 = cvt_pk_bf16(p1[0], p1[1]);
      unsigned a1 = cvt_pk_bf16(p0[2], p0[3]);
      unsigned a3 = cvt_pk_bf16(p1[2], p1[3]);
      permswap32(a0, a2);
      permswap32(a1, a3);
      unsigned b0 = cvt_pk_bf16(p2[0], p2[1]);
      unsigned b2 = cvt_pk_bf16(p3[0], p3[1]);
      unsigned b1 = cvt_pk_bf16(p2[2], p2[3]);
      unsigned b3 = cvt_pk_bf16(p3[2], p3[3]);
      permswap32(b0, b2);
      permswap32(b1, b3);
      union { unsigned u[4]; bf16x8 v; } pa0, pa1;
      pa0.u[0] = a0; pa0.u[1] = a1; pa0.u[2] = a2; pa0.u[3] = a3;
      pa1.u[0] = b0; pa1.u[1] = b1; pa1.u[2] = b2; pa1.u[3] = b3;

      // ---- PV ----
      __builtin_amdgcn_s_setprio(1);
#pragma unroll
      for (int t = 0; t < 4; ++t) {
        oacc[X][t] = __builtin_amdgcn_mfma_f32_16x16x32_bf16(pa0.v, vb[0][t], oacc[X][t], 0, 0, 0);
        oacc[X][t] = __builtin_amdgcn_mfma_f32_16x16x32_bf16(pa1.v, vb[1][t], oacc[X][t], 0, 0, 0);
      }
      __builtin_amdgcn_s_setprio(0);
    }
  }

  // ---- epilogue: accumulate partials (4 contributions/elem) ----
  const int b = bh >> 3, h = bh & 7;
#pragma unroll
  for (int X = 0; X < 4; ++X)
#pragma unroll
    for (int r = 0; r < 4; ++r) {
      float* op = P + (size_t)(b * SEQ + qbase + 16 * X + 4 * g + r) * EMB + h * 64;
#pragma unroll
      for (int t = 0; t < 4; ++t) atomicAdd(&op[16 * t + ln], oacc[X][t][r]);
    }
  if (g == 0) {
#pragma unroll
    for (int X = 0; X < 4; ++X)
      atomicAdd(&L[(size_t)(b * SEQ + qbase + 16 * X + ln) * NHEADS + h], denom[X]);
  }
}

// ---------------------------------------------------------------------------
// normalize: A_bf16[row][e] = P[row][e] / L[row][h],  8 elems/thread
// ---------------------------------------------------------------------------
__global__ __launch_bounds__(256) void normalize_o(const float* __restrict__ P,
                                                   const float* __restrict__ L,
                                                   ushort* __restrict__ A) {
  const int i = blockIdx.x * 256 + threadIdx.x;
  const int row = i >> 6;
  const int c = (i & 63) * 8;
  const int h = c >> 6;
  const float inv = 1.0f / L[(size_t)row * NHEADS + h];
  const float4 p0 = *(const float4*)&P[(size_t)row * EMB + c];
  const float4 p1 = *(const float4*)&P[(size_t)row * EMB + c + 4];
  uint4 o;
  o.x = cvt_pk_bf16(p0.x * inv, p0.y * inv);
  o.y = cvt_pk_bf16(p0.z * inv, p0.w * inv);
  o.z = cvt_pk_bf16(p1.x * inv, p1.y * inv);
  o.w = cvt_pk_bf16(p1.z * inv, p1.w * inv);
  ((uint4*)A)[i] = o;
}

// ---------------------------------------------------------------------------
extern "C" void kernel_launch(void* const* d_in, const int* in_sizes, int n_in,
                              void* d_out, int out_size, void* d_ws, size_t ws_size,
                              hipStream_t stream) {
  const float* q  = (const float*)d_in[0];
  const float* wq = (const float*)d_in[1];
  const float* bq = (const float*)d_in[2];
  const float* wk = (const float*)d_in[3];
  const float* bk = (const float*)d_in[4];
  const float* wv = (const float*)d_in[5];
  const float* bv = (const float*)d_in[6];
  const float* wo = (const float*)d_in[7];
  const float* bo = (const float*)d_in[8];
  float* out = (float*)d_out;

  const size_t XSZ = (size_t)MTOT * INDIM;
  const size_t WSZ = (size_t)EMB * INDIM;
  const size_t QSZ = (size_t)BATCH * NHEADS * SEQ * DH;
  ushort* wsX = (ushort*)d_ws;
  ushort* wsW = wsX + XSZ;
  ushort* wsQ = wsW + 4 * WSZ;
  ushort* wsK = wsQ + QSZ;
  ushort* wsVT = wsK + QSZ;
  float*  wsP = (float*)(wsVT + QSZ);
  float*  wsL = wsP + (size_t)MTOT * EMB;
  ushort* wsA = wsQ;   // overlay: Q dead after attn completes

  const dim3 blk(256);

  conv_bf16<<<dim3(XSZ / 8 / 256), blk, 0, stream>>>(q, wsX, XSZ / 8);
  conv_bf16_w4<<<dim3(WSZ / 8 / 256, 4), blk, 0, stream>>>(wq, wk, wv, wo, wsW, WSZ / 8);

  mfma_gemm<0><<<dim3(MTOT / 128, 1536 / 128), blk, 0, stream>>>(
      wsX, wsW, bq, bk, bv, wsQ, wsK, wsVT, nullptr);

  hipMemsetAsync(wsP, 0, (size_t)MTOT * EMB * sizeof(float) +
                          (size_t)MTOT * NHEADS * sizeof(float), stream);

  attn_mfma<<<dim3(1024), blk, 0, stream>>>(wsQ, wsK, wsVT, wsP, wsL);

  normalize_o<<<dim3(MTOT * EMB / 8 / 256), blk, 0, stream>>>(wsP, wsL, wsA);

  mfma_gemm<1><<<dim3(MTOT / 128, EMB / 128), blk, 0, stream>>>(
      wsA, wsW + 3 * WSZ, bo, nullptr, nullptr, nullptr, nullptr, nullptr, out);
}

// Round 11
// 107.552 us; speedup vs baseline: 1.3188x; 1.3188x over previous
//
#include <hip/hip_runtime.h>
#include <hip/hip_bf16.h>
#include <math.h>

#define SEQ    2048
#define DH     64
#define EMB    512
#define INDIM  512
#define NHEADS 8
#define BATCH  4
#define MTOT   (BATCH * SEQ)   // 8192

typedef __attribute__((ext_vector_type(8))) short bf16x8;   // 8 bf16 = 4 VGPR
typedef __attribute__((ext_vector_type(4))) float f32x4;

__device__ __forceinline__ ushort f2bf(float x) {
  union { float f; unsigned u; } v; v.f = x;
  unsigned r = v.u + 0x7FFFu + ((v.u >> 16) & 1u);   // RNE
  return (ushort)(r >> 16);
}

// packed f32x2 -> bf16x2 (single HW op)
__device__ __forceinline__ unsigned cvt_pk_bf16(float lo, float hi) {
  unsigned r;
  asm("v_cvt_pk_bf16_f32 %0, %1, %2" : "=v"(r) : "v"(lo), "v"(hi));
  return r;
}

// raw v_exp_f32 (exp2); args bounded (static-max softmax)
__device__ __forceinline__ float fast_exp2(float x) {
  float r;
  asm("v_exp_f32 %0, %1" : "=v"(r) : "v"(x));
  return r;
}

// v_permlane32_swap_b32: after: x = [x.h0, y.h0], y = [x.h1, y.h1] (lane halves)
__device__ __forceinline__ void permswap32(unsigned &x, unsigned &y) {
  asm("v_permlane32_swap_b32 %0, %1" : "+v"(x), "+v"(y));
}

// ---------------------------------------------------------------------------
// f32 -> bf16 conversion, 8 elems/thread
// ---------------------------------------------------------------------------
__global__ __launch_bounds__(256) void conv_bf16(const float* __restrict__ src,
                                                 ushort* __restrict__ dst, int n8) {
  const int i = blockIdx.x * 256 + threadIdx.x;
  if (i >= n8) return;
  const float4 a = ((const float4*)src)[i * 2];
  const float4 b = ((const float4*)src)[i * 2 + 1];
  uint4 o;
  o.x = cvt_pk_bf16(a.x, a.y);
  o.y = cvt_pk_bf16(a.z, a.w);
  o.z = cvt_pk_bf16(b.x, b.y);
  o.w = cvt_pk_bf16(b.z, b.w);
  ((uint4*)dst)[i] = o;
}

// 4 weight matrices in one launch (blockIdx.y selects)
__global__ __launch_bounds__(256) void conv_bf16_w4(
    const float* __restrict__ w0, const float* __restrict__ w1,
    const float* __restrict__ w2, const float* __restrict__ w3,
    ushort* __restrict__ dst, int n8per) {
  const int i = blockIdx.x * 256 + threadIdx.x;
  if (i >= n8per) return;
  const float* src = (blockIdx.y == 0) ? w0 : (blockIdx.y == 1) ? w1
                   : (blockIdx.y == 2) ? w2 : w3;
  ushort* d = dst + (size_t)blockIdx.y * n8per * 8;
  const float4 a = ((const float4*)src)[i * 2];
  const float4 b = ((const float4*)src)[i * 2 + 1];
  uint4 o;
  o.x = cvt_pk_bf16(a.x, a.y);
  o.y = cvt_pk_bf16(a.z, a.w);
  o.z = cvt_pk_bf16(b.x, b.y);
  o.w = cvt_pk_bf16(b.z, b.w);
  ((uint4*)d)[i] = o;
}

// ---------------------------------------------------------------------------
// MFMA GEMM, m97 structure: 128x128 tile, BK=32, 4 waves, 4x4 16x16 frags/wave,
// global_load_lds width 16.
// MODE 0: fused QKV (N=1536). which=bn>>9: 0->Q (pre-scaled by 0.125*log2e),
//         1->K bf16 [B,H,N,Dh]; 2->V^T bf16 [B,H,Dh,N] via LDS transpose.
// MODE 1: out-projection, f32 out [M][EMB] + bias.
// ---------------------------------------------------------------------------
template <int MODE>
__global__ __launch_bounds__(256) void mfma_gemm(
    const ushort* __restrict__ A, const ushort* __restrict__ W,
    const float* __restrict__ b0, const float* __restrict__ b1,
    const float* __restrict__ b2,
    ushort* __restrict__ outQ, ushort* __restrict__ outK,
    ushort* __restrict__ outVT, float* __restrict__ outF) {
  __shared__ __align__(16) char smem[MODE == 0 ? 35840 : 16384];
  ushort* As = (ushort*)smem;            // [128][32] bf16 = 8 KB
  ushort* Bs = (ushort*)(smem + 8192);   // [128][32] bf16 = 8 KB
  ushort* Tl = (ushort*)smem;            // epilogue transpose [128][140]

  const int bm = blockIdx.x * 128;
  const int bn = blockIdx.y * 128;
  const int tid = threadIdx.x;
  const int wave = tid >> 6, lane = tid & 63;
  const int g = lane >> 4, ln = lane & 15;
  const int wr = wave >> 1, wc = wave & 1;

  f32x4 acc[4][4];
#pragma unroll
  for (int m = 0; m < 4; ++m)
#pragma unroll
    for (int n = 0; n < 4; ++n) acc[m][n] = (f32x4){0.f, 0.f, 0.f, 0.f};

  const size_t a_base = (size_t)(bm + wave * 16 + (lane >> 2)) * INDIM + (lane & 3) * 8;
  const size_t b_base = (size_t)(bn + wave * 16 + (lane >> 2)) * INDIM + (lane & 3) * 8;
  ushort* ldsA0 = As + wave * 512;
  ushort* ldsA1 = As + 2048 + wave * 512;
  ushort* ldsB0 = Bs + wave * 512;
  ushort* ldsB1 = Bs + 2048 + wave * 512;

  for (int k0 = 0; k0 < INDIM; k0 += 32) {
    __syncthreads();
    __builtin_amdgcn_global_load_lds(
        (const __attribute__((address_space(1))) void*)(A + a_base + k0),
        (__attribute__((address_space(3))) void*)ldsA0, 16, 0, 0);
    __builtin_amdgcn_global_load_lds(
        (const __attribute__((address_space(1))) void*)(A + a_base + 64 * INDIM + k0),
        (__attribute__((address_space(3))) void*)ldsA1, 16, 0, 0);
    __builtin_amdgcn_global_load_lds(
        (const __attribute__((address_space(1))) void*)(W + b_base + k0),
        (__attribute__((address_space(3))) void*)ldsB0, 16, 0, 0);
    __builtin_amdgcn_global_load_lds(
        (const __attribute__((address_space(1))) void*)(W + b_base + 64 * INDIM + k0),
        (__attribute__((address_space(3))) void*)ldsB1, 16, 0, 0);
    __syncthreads();

    bf16x8 af[4], bfv[4];
#pragma unroll
    for (int m = 0; m < 4; ++m)
      af[m] = *(const bf16x8*)&As[(64 * wr + 16 * m + ln) * 32 + 8 * g];
#pragma unroll
    for (int n = 0; n < 4; ++n)
      bfv[n] = *(const bf16x8*)&Bs[(64 * wc + 16 * n + ln) * 32 + 8 * g];
#pragma unroll
    for (int m = 0; m < 4; ++m)
#pragma unroll
      for (int n = 0; n < 4; ++n)
        acc[m][n] = __builtin_amdgcn_mfma_f32_16x16x32_bf16(af[m], bfv[n], acc[m][n], 0, 0, 0);
  }

  // ---- epilogue ----  C: row = bm+64wr+16m+4g+r, col e = bn+64wc+16n+ln
  if (MODE == 1) {
#pragma unroll
    for (int n = 0; n < 4; ++n) {
      const int e = bn + 64 * wc + 16 * n + ln;
      const float bv = b0[e];
#pragma unroll
      for (int m = 0; m < 4; ++m)
#pragma unroll
        for (int r = 0; r < 4; ++r) {
          const int row = bm + 64 * wr + 16 * m + 4 * g + r;
          outF[(size_t)row * EMB + e] = acc[m][n][r] + bv;
        }
    }
    return;
  }

  const int which = bn >> 9;
  const float* bias = (which == 0) ? b0 : (which == 1) ? b1 : b2;

  if (which < 2) {
    // Q gets the softmax scale folded in (log2 domain): 0.125 * log2(e)
    const float scl = (which == 0) ? 0.18033688f : 1.0f;
    ushort* dst = (which == 0) ? outQ : outK;
#pragma unroll
    for (int n = 0; n < 4; ++n) {
      const int e = (bn & 511) + 64 * wc + 16 * n + ln;
      const float bv = bias[e];
      const int h = e >> 6, d = e & 63;
#pragma unroll
      for (int m = 0; m < 4; ++m)
#pragma unroll
        for (int r = 0; r < 4; ++r) {
          const int row = bm + 64 * wr + 16 * m + 4 * g + r;
          const int b = row >> 11, nn = row & (SEQ - 1);
          dst[(((size_t)(b * NHEADS + h) * SEQ) + nn) * DH + d] =
              f2bf((acc[m][n][r] + bv) * scl);
        }
    }
  } else {
    // V: transpose through LDS, write V^T [B,H,Dh,N]
    __syncthreads();
#pragma unroll
    for (int n = 0; n < 4; ++n) {
      const int cl = 64 * wc + 16 * n + ln;
      const float bv = bias[(bn & 511) + cl];
#pragma unroll
      for (int m = 0; m < 4; ++m)
#pragma unroll
        for (int r = 0; r < 4; ++r) {
          const int rl = 64 * wr + 16 * m + 4 * g + r;
          Tl[cl * 140 + rl] = f2bf(acc[m][n][r] + bv);
        }
    }
    __syncthreads();
    const int c = tid >> 1;
    const int rh = (tid & 1) * 64;
    const int e = (bn & 511) + c;
    const int h = e >> 6, d = e & 63;
    const int b = bm >> 11;
    const int nn0 = (bm & (SEQ - 1)) + rh;
    ushort* drow = outVT + (((size_t)(b * NHEADS + h) * DH) + d) * SEQ + nn0;
#pragma unroll
    for (int j = 0; j < 8; ++j)
      *(bf16x8*)&drow[j * 8] = *(const bf16x8*)&Tl[c * 140 + rh + j * 8];
  }
}

// ---------------------------------------------------------------------------
// MFMA flash attention: R5's verified shell (4 waves x 32 q-rows, KV-step 64,
// grid 512, no split, direct bf16 O write) + R7/R8's verified in-register-P:
// K staged pi-permuted (rows 4-7 <-> 8-11 per 16-tile), cvt_pk + 2x
// permlane32_swap turn the swapped-QK^T output into PV A-fragments with ZERO
// P LDS traffic. Ones-tile dropped; denominator = in-lane f32 sum + 2
// shfl_xor (R7-verified), inverse distributed by __shfl in the epilogue.
// Static-max softmax (R4 bound); Q pre-scaled by 0.125*log2e (exp2 domain).
// T14 prefetch + lgkmcnt/s_barrier (R5-verified sync); XCD swizzle.
// ---------------------------------------------------------------------------
__global__ __launch_bounds__(256) void attn_mfma(const ushort* __restrict__ Q,
                                                 const ushort* __restrict__ K,
                                                 const ushort* __restrict__ VT,
                                                 ushort* __restrict__ O) {
  __shared__ __align__(16) ushort Kl[64 * 72];     // [kv(pi-permuted)][d] padded
  __shared__ __align__(16) ushort Vl[64 * 72];     // [d][kv] padded

  const int tid = threadIdx.x;
  const int wave = tid >> 6, lane = tid & 63;
  const int g = lane >> 4, ln = lane & 15;

  // XCD swizzle over 512 wgs: swz = (orig%8)*64 + orig/8 (bijective; 4 bh/XCD)
  const int orig = blockIdx.x;
  const int swz = (orig & 7) * 64 + (orig >> 3);
  const int bh = swz >> 4;            // 0..31
  const int qx = swz & 15;            // 0..15
  const int qbase = qx * 128 + wave * 32;

  const ushort* Qb = Q + ((size_t)bh * SEQ + qbase) * DH;
  const ushort* Kb = K + (size_t)bh * SEQ * DH;
  const ushort* Vb = VT + (size_t)bh * DH * SEQ;

  const bf16x8 qfA0 = *(const bf16x8*)&Qb[ln * DH + 8 * g];
  const bf16x8 qfA1 = *(const bf16x8*)&Qb[ln * DH + 32 + 8 * g];
  const bf16x8 qfB0 = *(const bf16x8*)&Qb[(16 + ln) * DH + 8 * g];
  const bf16x8 qfB1 = *(const bf16x8*)&Qb[(16 + ln) * DH + 32 + 8 * g];

  f32x4 oaccA[4], oaccB[4];
#pragma unroll
  for (int t = 0; t < 4; ++t) {
    oaccA[t] = (f32x4){0.f, 0.f, 0.f, 0.f};
    oaccB[t] = (f32x4){0.f, 0.f, 0.f, 0.f};
  }
  float denomA = 0.f, denomB = 0.f;

  const int skv = tid >> 3, sd = (tid & 7) * 8;   // K staging (rows skv, skv+32)
  const int dt = tid >> 2, kc = (tid & 3) * 8;    // V staging
  // pi-permuted LDS rows for K: XOR 12 where bit2^bit3 (swaps rows 4-7 <-> 8-11)
  const int pr0 = skv ^ (((((skv >> 2) ^ (skv >> 3)) & 1)) * 12);
  const int s32 = skv + 32;
  const int pr1 = s32 ^ (((((s32 >> 2) ^ (s32 >> 3)) & 1)) * 12);

  // preload tile 0
  bf16x8 k0v = *(const bf16x8*)&Kb[(size_t)skv * DH + sd];
  bf16x8 k1v = *(const bf16x8*)&Kb[(size_t)(32 + skv) * DH + sd];
  bf16x8 v0v = *(const bf16x8*)&Vb[(size_t)dt * SEQ + kc];
  bf16x8 v1v = *(const bf16x8*)&Vb[(size_t)dt * SEQ + 32 + kc];

  for (int kv0 = 0; kv0 < SEQ; kv0 += 64) {
    __syncthreads();   // prev tile consumed
    *(bf16x8*)&Kl[pr0 * 72 + sd] = k0v;
    *(bf16x8*)&Kl[pr1 * 72 + sd] = k1v;
    *(bf16x8*)&Vl[dt * 72 + kc] = v0v;
    *(bf16x8*)&Vl[dt * 72 + 32 + kc] = v1v;

    // issue next tile's loads (fly during compute; raw barrier won't drain vmcnt)
    const int nxt = (kv0 + 64 < SEQ) ? kv0 + 64 : kv0;
    k0v = *(const bf16x8*)&Kb[(size_t)(nxt + skv) * DH + sd];
    k1v = *(const bf16x8*)&Kb[(size_t)(nxt + 32 + skv) * DH + sd];
    v0v = *(const bf16x8*)&Vb[(size_t)dt * SEQ + nxt + kc];
    v1v = *(const bf16x8*)&Vb[(size_t)dt * SEQ + nxt + 32 + kc];

    asm volatile("s_waitcnt lgkmcnt(0)" ::: "memory");
    __builtin_amdgcn_s_barrier();

    // ---- shared fragments, read ONCE, reused by both q-groups ----
    bf16x8 ka[4][2], vb[2][4];
#pragma unroll
    for (int t = 0; t < 4; ++t) {
      ka[t][0] = *(const bf16x8*)&Kl[(16 * t + ln) * 72 + 8 * g];
      ka[t][1] = *(const bf16x8*)&Kl[(16 * t + ln) * 72 + 32 + 8 * g];
    }
#pragma unroll
    for (int c = 0; c < 2; ++c)
#pragma unroll
      for (int t = 0; t < 4; ++t)
        vb[c][t] = *(const bf16x8*)&Vl[(16 * t + ln) * 72 + 32 * c + 8 * g];

    // ================= group A (q = qbase + ln) =================
    {
      f32x4 s0 = (f32x4){0.f, 0.f, 0.f, 0.f};
      f32x4 s1 = s0, s2 = s0, s3 = s0;
      __builtin_amdgcn_s_setprio(1);
      s0 = __builtin_amdgcn_mfma_f32_16x16x32_bf16(ka[0][0], qfA0, s0, 0, 0, 0);
      s1 = __builtin_amdgcn_mfma_f32_16x16x32_bf16(ka[1][0], qfA0, s1, 0, 0, 0);
      s2 = __builtin_amdgcn_mfma_f32_16x16x32_bf16(ka[2][0], qfA0, s2, 0, 0, 0);
      s3 = __builtin_amdgcn_mfma_f32_16x16x32_bf16(ka[3][0], qfA0, s3, 0, 0, 0);
      s0 = __builtin_amdgcn_mfma_f32_16x16x32_bf16(ka[0][1], qfA1, s0, 0, 0, 0);
      s1 = __builtin_amdgcn_mfma_f32_16x16x32_bf16(ka[1][1], qfA1, s1, 0, 0, 0);
      s2 = __builtin_amdgcn_mfma_f32_16x16x32_bf16(ka[2][1], qfA1, s2, 0, 0, 0);
      s3 = __builtin_amdgcn_mfma_f32_16x16x32_bf16(ka[3][1], qfA1, s3, 0, 0, 0);
      __builtin_amdgcn_s_setprio(0);

      float p0[4], p1[4], p2[4], p3[4];
#pragma unroll
      for (int r = 0; r < 4; ++r) {
        p0[r] = fast_exp2(s0[r]);
        p1[r] = fast_exp2(s1[r]);
        p2[r] = fast_exp2(s2[r]);
        p3[r] = fast_exp2(s3[r]);
      }
      float ds = ((p0[0] + p0[1]) + (p0[2] + p0[3]))
               + ((p1[0] + p1[1]) + (p1[2] + p1[3]))
               + ((p2[0] + p2[1]) + (p2[2] + p2[3]))
               + ((p3[0] + p3[1]) + (p3[2] + p3[3]));
      ds += __shfl_xor(ds, 16);
      ds += __shfl_xor(ds, 32);
      denomA += ds;

      unsigned a0 = cvt_pk_bf16(p0[0], p0[1]);
      unsigned a2 = cvt_pk_bf16(p1[0], p1[1]);
      unsigned a1 = cvt_pk_bf16(p0[2], p0[3]);
      unsigned a3 = cvt_pk_bf16(p1[2], p1[3]);
      permswap32(a0, a2);
      permswap32(a1, a3);
      unsigned b0 = cvt_pk_bf16(p2[0], p2[1]);
      unsigned b2 = cvt_pk_bf16(p3[0], p3[1]);
      unsigned b1 = cvt_pk_bf16(p2[2], p2[3]);
      unsigned b3 = cvt_pk_bf16(p3[2], p3[3]);
      permswap32(b0, b2);
      permswap32(b1, b3);
      union { unsigned u[4]; bf16x8 v; } pa0, pa1;
      pa0.u[0] = a0; pa0.u[1] = a1; pa0.u[2] = a2; pa0.u[3] = a3;
      pa1.u[0] = b0; pa1.u[1] = b1; pa1.u[2] = b2; pa1.u[3] = b3;

      __builtin_amdgcn_s_setprio(1);
#pragma unroll
      for (int t = 0; t < 4; ++t) {
        oaccA[t] = __builtin_amdgcn_mfma_f32_16x16x32_bf16(pa0.v, vb[0][t], oaccA[t], 0, 0, 0);
        oaccA[t] = __builtin_amdgcn_mfma_f32_16x16x32_bf16(pa1.v, vb[1][t], oaccA[t], 0, 0, 0);
      }
      __builtin_amdgcn_s_setprio(0);
    }

    // ================= group B (q = qbase + 16 + ln) =================
    {
      f32x4 s0 = (f32x4){0.f, 0.f, 0.f, 0.f};
      f32x4 s1 = s0, s2 = s0, s3 = s0;
      __builtin_amdgcn_s_setprio(1);
      s0 = __builtin_amdgcn_mfma_f32_16x16x32_bf16(ka[0][0], qfB0, s0, 0, 0, 0);
      s1 = __builtin_amdgcn_mfma_f32_16x16x32_bf16(ka[1][0], qfB0, s1, 0, 0, 0);
      s2 = __builtin_amdgcn_mfma_f32_16x16x32_bf16(ka[2][0], qfB0, s2, 0, 0, 0);
      s3 = __builtin_amdgcn_mfma_f32_16x16x32_bf16(ka[3][0], qfB0, s3, 0, 0, 0);
      s0 = __builtin_amdgcn_mfma_f32_16x16x32_bf16(ka[0][1], qfB1, s0, 0, 0, 0);
      s1 = __builtin_amdgcn_mfma_f32_16x16x32_bf16(ka[1][1], qfB1, s1, 0, 0, 0);
      s2 = __builtin_amdgcn_mfma_f32_16x16x32_bf16(ka[2][1], qfB1, s2, 0, 0, 0);
      s3 = __builtin_amdgcn_mfma_f32_16x16x32_bf16(ka[3][1], qfB1, s3, 0, 0, 0);
      __builtin_amdgcn_s_setprio(0);

      float p0[4], p1[4], p2[4], p3[4];
#pragma unroll
      for (int r = 0; r < 4; ++r) {
        p0[r] = fast_exp2(s0[r]);
        p1[r] = fast_exp2(s1[r]);
        p2[r] = fast_exp2(s2[r]);
        p3[r] = fast_exp2(s3[r]);
      }
      float ds = ((p0[0] + p0[1]) + (p0[2] + p0[3]))
               + ((p1[0] + p1[1]) + (p1[2] + p1[3]))
               + ((p2[0] + p2[1]) + (p2[2] + p2[3]))
               + ((p3[0] + p3[1]) + (p3[2] + p3[3]));
      ds += __shfl_xor(ds, 16);
      ds += __shfl_xor(ds, 32);
      denomB += ds;

      unsigned a0 = cvt_pk_bf16(p0[0], p0[1]);
      unsigned a2 = cvt_pk_bf16(p1[0], p1[1]);
      unsigned a1 = cvt_pk_bf16(p0[2], p0[3]);
      unsigned a3 = cvt_pk_bf16(p1[2], p1[3]);
      permswap32(a0, a2);
      permswap32(a1, a3);
      unsigned b0 = cvt_pk_bf16(p2[0], p2[1]);
      unsigned b2 = cvt_pk_bf16(p3[0], p3[1]);
      unsigned b1 = cvt_pk_bf16(p2[2], p2[3]);
      unsigned b3 = cvt_pk_bf16(p3[2], p3[3]);
      permswap32(b0, b2);
      permswap32(b1, b3);
      union { unsigned u[4]; bf16x8 v; } pa0, pa1;
      pa0.u[0] = a0; pa0.u[1] = a1; pa0.u[2] = a2; pa0.u[3] = a3;
      pa1.u[0] = b0; pa1.u[1] = b1; pa1.u[2] = b2; pa1.u[3] = b3;

      __builtin_amdgcn_s_setprio(1);
#pragma unroll
      for (int t = 0; t < 4; ++t) {
        oaccB[t] = __builtin_amdgcn_mfma_f32_16x16x32_bf16(pa0.v, vb[0][t], oaccB[t], 0, 0, 0);
        oaccB[t] = __builtin_amdgcn_mfma_f32_16x16x32_bf16(pa1.v, vb[1][t], oaccB[t], 0, 0, 0);
      }
      __builtin_amdgcn_s_setprio(0);
    }
  }

  // ---- epilogue: lane's denom is for q=ln (uniform over g); fetch per-row ----
  const float invA = 1.0f / denomA;
  const float invB = 1.0f / denomB;
  const int b = bh >> 3, h = bh & 7;
#pragma unroll
  for (int r = 0; r < 4; ++r) {
    const float irA = __shfl(invA, 4 * g + r);   // lane 4g+r has q=4g+r's denom
    const float irB = __shfl(invB, 4 * g + r);
    ushort* opA = O + ((size_t)(b * SEQ) + qbase + 4 * g + r) * EMB + h * 64;
    ushort* opB = O + ((size_t)(b * SEQ) + qbase + 16 + 4 * g + r) * EMB + h * 64;
#pragma unroll
    for (int t = 0; t < 4; ++t) {
      opA[16 * t + ln] = f2bf(oaccA[t][r] * irA);
      opB[16 * t + ln] = f2bf(oaccB[t][r] * irB);
    }
  }
}

// ---------------------------------------------------------------------------
extern "C" void kernel_launch(void* const* d_in, const int* in_sizes, int n_in,
                              void* d_out, int out_size, void* d_ws, size_t ws_size,
                              hipStream_t stream) {
  const float* q  = (const float*)d_in[0];
  const float* wq = (const float*)d_in[1];
  const float* bq = (const float*)d_in[2];
  const float* wk = (const float*)d_in[3];
  const float* bk = (const float*)d_in[4];
  const float* wv = (const float*)d_in[5];
  const float* bv = (const float*)d_in[6];
  const float* wo = (const float*)d_in[7];
  const float* bo = (const float*)d_in[8];
  float* out = (float*)d_out;

  const size_t XSZ = (size_t)MTOT * INDIM;
  const size_t WSZ = (size_t)EMB * INDIM;
  const size_t QSZ = (size_t)BATCH * NHEADS * SEQ * DH;
  ushort* wsX = (ushort*)d_ws;
  ushort* wsW = wsX + XSZ;
  ushort* wsQ = wsW + 4 * WSZ;
  ushort* wsK = wsQ + QSZ;
  ushort* wsVT = wsK + QSZ;
  ushort* wsA = wsVT + QSZ;   // attn output bf16 [B,N,EMB]

  const dim3 blk(256);

  conv_bf16<<<dim3(XSZ / 8 / 256), blk, 0, stream>>>(q, wsX, XSZ / 8);
  conv_bf16_w4<<<dim3(WSZ / 8 / 256, 4), blk, 0, stream>>>(wq, wk, wv, wo, wsW, WSZ / 8);

  mfma_gemm<0><<<dim3(MTOT / 128, 1536 / 128), blk, 0, stream>>>(
      wsX, wsW, bq, bk, bv, wsQ, wsK, wsVT, nullptr);

  attn_mfma<<<dim3(512), blk, 0, stream>>>(wsQ, wsK, wsVT, wsA);

  mfma_gemm<1><<<dim3(MTOT / 128, EMB / 128), blk, 0, stream>>>(
      wsA, wsW + 3 * WSZ, bo, nullptr, nullptr, nullptr, nullptr, nullptr, out);
}

// Round 12
// 103.399 us; speedup vs baseline: 1.3717x; 1.0402x over previous
//
#include <hip/hip_runtime.h>
#include <hip/hip_bf16.h>
#include <math.h>

#define SEQ    2048
#define DH     64
#define EMB    512
#define INDIM  512
#define NHEADS 8
#define BATCH  4
#define MTOT   (BATCH * SEQ)   // 8192

typedef __attribute__((ext_vector_type(8))) short bf16x8;   // 8 bf16 = 4 VGPR
typedef __attribute__((ext_vector_type(4))) float f32x4;

__device__ __forceinline__ ushort f2bf(float x) {
  union { float f; unsigned u; } v; v.f = x;
  unsigned r = v.u + 0x7FFFu + ((v.u >> 16) & 1u);   // RNE
  return (ushort)(r >> 16);
}

// packed f32x2 -> bf16x2 (single HW op)
__device__ __forceinline__ unsigned cvt_pk_bf16(float lo, float hi) {
  unsigned r;
  asm("v_cvt_pk_bf16_f32 %0, %1, %2" : "=v"(r) : "v"(lo), "v"(hi));
  return r;
}

// raw v_exp_f32 (exp2); args bounded (static-max softmax)
__device__ __forceinline__ float fast_exp2(float x) {
  float r;
  asm("v_exp_f32 %0, %1" : "=v"(r) : "v"(x));
  return r;
}

// v_permlane32_swap_b32: after: x = [x.h0, y.h0], y = [x.h1, y.h1] (lane halves)
__device__ __forceinline__ void permswap32(unsigned &x, unsigned &y) {
  asm("v_permlane32_swap_b32 %0, %1" : "+v"(x), "+v"(y));
}

// ---------------------------------------------------------------------------
// f32 -> bf16 conversion, 8 elems/thread
// ---------------------------------------------------------------------------
__global__ __launch_bounds__(256) void conv_bf16(const float* __restrict__ src,
                                                 ushort* __restrict__ dst, int n8) {
  const int i = blockIdx.x * 256 + threadIdx.x;
  if (i >= n8) return;
  const float4 a = ((const float4*)src)[i * 2];
  const float4 b = ((const float4*)src)[i * 2 + 1];
  uint4 o;
  o.x = cvt_pk_bf16(a.x, a.y);
  o.y = cvt_pk_bf16(a.z, a.w);
  o.z = cvt_pk_bf16(b.x, b.y);
  o.w = cvt_pk_bf16(b.z, b.w);
  ((uint4*)dst)[i] = o;
}

// 4 weight matrices in one launch (blockIdx.y selects)
__global__ __launch_bounds__(256) void conv_bf16_w4(
    const float* __restrict__ w0, const float* __restrict__ w1,
    const float* __restrict__ w2, const float* __restrict__ w3,
    ushort* __restrict__ dst, int n8per) {
  const int i = blockIdx.x * 256 + threadIdx.x;
  if (i >= n8per) return;
  const float* src = (blockIdx.y == 0) ? w0 : (blockIdx.y == 1) ? w1
                   : (blockIdx.y == 2) ? w2 : w3;
  ushort* d = dst + (size_t)blockIdx.y * n8per * 8;
  const float4 a = ((const float4*)src)[i * 2];
  const float4 b = ((const float4*)src)[i * 2 + 1];
  uint4 o;
  o.x = cvt_pk_bf16(a.x, a.y);
  o.y = cvt_pk_bf16(a.z, a.w);
  o.z = cvt_pk_bf16(b.x, b.y);
  o.w = cvt_pk_bf16(b.z, b.w);
  ((uint4*)d)[i] = o;
}

// ---------------------------------------------------------------------------
// MFMA GEMM, m97 structure: 128x128 tile, BK=32, 4 waves, 4x4 16x16 frags/wave,
// global_load_lds width 16.
// MODE 0: fused QKV (N=1536). which=bn>>9: 0->Q (pre-scaled by 0.125*log2e),
//         1->K bf16 [B,H,N,Dh]; 2->V^T bf16 [B,H,Dh,N] via LDS transpose.
// MODE 1: out-projection, f32 out [M][EMB] + bias.
// ---------------------------------------------------------------------------
template <int MODE>
__global__ __launch_bounds__(256) void mfma_gemm(
    const ushort* __restrict__ A, const ushort* __restrict__ W,
    const float* __restrict__ b0, const float* __restrict__ b1,
    const float* __restrict__ b2,
    ushort* __restrict__ outQ, ushort* __restrict__ outK,
    ushort* __restrict__ outVT, float* __restrict__ outF) {
  __shared__ __align__(16) char smem[MODE == 0 ? 35840 : 16384];
  ushort* As = (ushort*)smem;            // [128][32] bf16 = 8 KB
  ushort* Bs = (ushort*)(smem + 8192);   // [128][32] bf16 = 8 KB
  ushort* Tl = (ushort*)smem;            // epilogue transpose [128][140]

  const int bm = blockIdx.x * 128;
  const int bn = blockIdx.y * 128;
  const int tid = threadIdx.x;
  const int wave = tid >> 6, lane = tid & 63;
  const int g = lane >> 4, ln = lane & 15;
  const int wr = wave >> 1, wc = wave & 1;

  f32x4 acc[4][4];
#pragma unroll
  for (int m = 0; m < 4; ++m)
#pragma unroll
    for (int n = 0; n < 4; ++n) acc[m][n] = (f32x4){0.f, 0.f, 0.f, 0.f};

  const size_t a_base = (size_t)(bm + wave * 16 + (lane >> 2)) * INDIM + (lane & 3) * 8;
  const size_t b_base = (size_t)(bn + wave * 16 + (lane >> 2)) * INDIM + (lane & 3) * 8;
  ushort* ldsA0 = As + wave * 512;
  ushort* ldsA1 = As + 2048 + wave * 512;
  ushort* ldsB0 = Bs + wave * 512;
  ushort* ldsB1 = Bs + 2048 + wave * 512;

  for (int k0 = 0; k0 < INDIM; k0 += 32) {
    __syncthreads();
    __builtin_amdgcn_global_load_lds(
        (const __attribute__((address_space(1))) void*)(A + a_base + k0),
        (__attribute__((address_space(3))) void*)ldsA0, 16, 0, 0);
    __builtin_amdgcn_global_load_lds(
        (const __attribute__((address_space(1))) void*)(A + a_base + 64 * INDIM + k0),
        (__attribute__((address_space(3))) void*)ldsA1, 16, 0, 0);
    __builtin_amdgcn_global_load_lds(
        (const __attribute__((address_space(1))) void*)(W + b_base + k0),
        (__attribute__((address_space(3))) void*)ldsB0, 16, 0, 0);
    __builtin_amdgcn_global_load_lds(
        (const __attribute__((address_space(1))) void*)(W + b_base + 64 * INDIM + k0),
        (__attribute__((address_space(3))) void*)ldsB1, 16, 0, 0);
    __syncthreads();

    bf16x8 af[4], bfv[4];
#pragma unroll
    for (int m = 0; m < 4; ++m)
      af[m] = *(const bf16x8*)&As[(64 * wr + 16 * m + ln) * 32 + 8 * g];
#pragma unroll
    for (int n = 0; n < 4; ++n)
      bfv[n] = *(const bf16x8*)&Bs[(64 * wc + 16 * n + ln) * 32 + 8 * g];
#pragma unroll
    for (int m = 0; m < 4; ++m)
#pragma unroll
      for (int n = 0; n < 4; ++n)
        acc[m][n] = __builtin_amdgcn_mfma_f32_16x16x32_bf16(af[m], bfv[n], acc[m][n], 0, 0, 0);
  }

  // ---- epilogue ----  C: row = bm+64wr+16m+4g+r, col e = bn+64wc+16n+ln
  if (MODE == 1) {
#pragma unroll
    for (int n = 0; n < 4; ++n) {
      const int e = bn + 64 * wc + 16 * n + ln;
      const float bv = b0[e];
#pragma unroll
      for (int m = 0; m < 4; ++m)
#pragma unroll
        for (int r = 0; r < 4; ++r) {
          const int row = bm + 64 * wr + 16 * m + 4 * g + r;
          outF[(size_t)row * EMB + e] = acc[m][n][r] + bv;
        }
    }
    return;
  }

  const int which = bn >> 9;
  const float* bias = (which == 0) ? b0 : (which == 1) ? b1 : b2;

  if (which < 2) {
    // Q gets the softmax scale folded in (log2 domain): 0.125 * log2(e)
    const float scl = (which == 0) ? 0.18033688f : 1.0f;
    ushort* dst = (which == 0) ? outQ : outK;
#pragma unroll
    for (int n = 0; n < 4; ++n) {
      const int e = (bn & 511) + 64 * wc + 16 * n + ln;
      const float bv = bias[e];
      const int h = e >> 6, d = e & 63;
#pragma unroll
      for (int m = 0; m < 4; ++m)
#pragma unroll
        for (int r = 0; r < 4; ++r) {
          const int row = bm + 64 * wr + 16 * m + 4 * g + r;
          const int b = row >> 11, nn = row & (SEQ - 1);
          dst[(((size_t)(b * NHEADS + h) * SEQ) + nn) * DH + d] =
              f2bf((acc[m][n][r] + bv) * scl);
        }
    }
  } else {
    // V: transpose through LDS, write V^T [B,H,Dh,N]
    __syncthreads();
#pragma unroll
    for (int n = 0; n < 4; ++n) {
      const int cl = 64 * wc + 16 * n + ln;
      const float bv = bias[(bn & 511) + cl];
#pragma unroll
      for (int m = 0; m < 4; ++m)
#pragma unroll
        for (int r = 0; r < 4; ++r) {
          const int rl = 64 * wr + 16 * m + 4 * g + r;
          Tl[cl * 140 + rl] = f2bf(acc[m][n][r] + bv);
        }
    }
    __syncthreads();
    const int c = tid >> 1;
    const int rh = (tid & 1) * 64;
    const int e = (bn & 511) + c;
    const int h = e >> 6, d = e & 63;
    const int b = bm >> 11;
    const int nn0 = (bm & (SEQ - 1)) + rh;
    ushort* drow = outVT + (((size_t)(b * NHEADS + h) * DH) + d) * SEQ + nn0;
#pragma unroll
    for (int j = 0; j < 8; ++j)
      *(bf16x8*)&drow[j * 8] = *(const bf16x8*)&Tl[c * 140 + rh + j * 8];
  }
}

// ---------------------------------------------------------------------------
// MFMA flash attention (R10-verified data path + two issue-budget cuts):
// (a) DOUBLE-BUFFERED LDS: stage tile t+1 into buf B while computing tile t
//     from buf A -> ONE lgkmcnt(0)+s_barrier per iter (was 2); global
//     prefetch distance 2. Indices identical to R10, only buffer parity new.
// (b) DENOMINATOR VIA MFMA: oaccD = mfma(pa, ones, oaccD) on the idle matrix
//     pipe replaces 28 VALU adds + 4 serial shfl_xor per iter; denominator
//     lands lane-local in oaccD[r] (col ln uniform), so the epilogue needs
//     no __shfl at all.
// In-register P (pi-permuted K staging + cvt_pk + permlane32_swap), static-max
// exp2 softmax (Q pre-scaled by 0.125*log2e), XCD swizzle, direct bf16 O.
// ---------------------------------------------------------------------------
__global__ __launch_bounds__(256) void attn_mfma(const ushort* __restrict__ Q,
                                                 const ushort* __restrict__ K,
                                                 const ushort* __restrict__ VT,
                                                 ushort* __restrict__ O) {
  __shared__ __align__(16) ushort Kl[2][64 * 72];  // [buf][kv(pi-permuted)][d]
  __shared__ __align__(16) ushort Vl[2][64 * 72];  // [buf][d][kv]

  const int tid = threadIdx.x;
  const int wave = tid >> 6, lane = tid & 63;
  const int g = lane >> 4, ln = lane & 15;

  // XCD swizzle over 512 wgs: swz = (orig%8)*64 + orig/8 (bijective; 4 bh/XCD)
  const int orig = blockIdx.x;
  const int swz = (orig & 7) * 64 + (orig >> 3);
  const int bh = swz >> 4;            // 0..31
  const int qx = swz & 15;            // 0..15
  const int qbase = qx * 128 + wave * 32;

  const ushort* Qb = Q + ((size_t)bh * SEQ + qbase) * DH;
  const ushort* Kb = K + (size_t)bh * SEQ * DH;
  const ushort* Vb = VT + (size_t)bh * DH * SEQ;

  const bf16x8 qfA0 = *(const bf16x8*)&Qb[ln * DH + 8 * g];
  const bf16x8 qfA1 = *(const bf16x8*)&Qb[ln * DH + 32 + 8 * g];
  const bf16x8 qfB0 = *(const bf16x8*)&Qb[(16 + ln) * DH + 8 * g];
  const bf16x8 qfB1 = *(const bf16x8*)&Qb[(16 + ln) * DH + 32 + 8 * g];

  // ones B-fragment for the denominator MFMA (bf16 1.0 = 0x3F80)
  bf16x8 vones;
#pragma unroll
  for (int i = 0; i < 8; ++i) vones[i] = (short)0x3F80;

  f32x4 oaccA[4], oaccB[4];
  f32x4 oaccDA = (f32x4){0.f, 0.f, 0.f, 0.f};
  f32x4 oaccDB = (f32x4){0.f, 0.f, 0.f, 0.f};
#pragma unroll
  for (int t = 0; t < 4; ++t) {
    oaccA[t] = (f32x4){0.f, 0.f, 0.f, 0.f};
    oaccB[t] = (f32x4){0.f, 0.f, 0.f, 0.f};
  }

  const int skv = tid >> 3, sd = (tid & 7) * 8;   // K staging (rows skv, skv+32)
  const int dt = tid >> 2, kc = (tid & 3) * 8;    // V staging
  // pi-permuted LDS rows for K: XOR 12 where bit2^bit3 (swaps rows 4-7 <-> 8-11)
  const int pr0 = skv ^ (((((skv >> 2) ^ (skv >> 3)) & 1)) * 12);
  const int s32 = skv + 32;
  const int pr1 = s32 ^ (((((s32 >> 2) ^ (s32 >> 3)) & 1)) * 12);

  // ---- preload: tile 0 -> regs -> buf0; tile 1 -> regs ----
  bf16x8 k0v = *(const bf16x8*)&Kb[(size_t)skv * DH + sd];
  bf16x8 k1v = *(const bf16x8*)&Kb[(size_t)(32 + skv) * DH + sd];
  bf16x8 v0v = *(const bf16x8*)&Vb[(size_t)dt * SEQ + kc];
  bf16x8 v1v = *(const bf16x8*)&Vb[(size_t)dt * SEQ + 32 + kc];
  *(bf16x8*)&Kl[0][pr0 * 72 + sd] = k0v;
  *(bf16x8*)&Kl[0][pr1 * 72 + sd] = k1v;
  *(bf16x8*)&Vl[0][dt * 72 + kc] = v0v;
  *(bf16x8*)&Vl[0][dt * 72 + 32 + kc] = v1v;
  k0v = *(const bf16x8*)&Kb[(size_t)(64 + skv) * DH + sd];
  k1v = *(const bf16x8*)&Kb[(size_t)(96 + skv) * DH + sd];
  v0v = *(const bf16x8*)&Vb[(size_t)dt * SEQ + 64 + kc];
  v1v = *(const bf16x8*)&Vb[(size_t)dt * SEQ + 96 + kc];
  asm volatile("s_waitcnt lgkmcnt(0)" ::: "memory");
  __builtin_amdgcn_s_barrier();

  for (int it = 0; it < 32; ++it) {
    const int cur = it & 1;
    ushort* Kc = Kl[cur];
    ushort* Vc = Vl[cur];

    // stage tile it+1 into the other buffer (regs hold it+1)
    if (it < 31) {
      ushort* Kn = Kl[cur ^ 1];
      ushort* Vn = Vl[cur ^ 1];
      *(bf16x8*)&Kn[pr0 * 72 + sd] = k0v;
      *(bf16x8*)&Kn[pr1 * 72 + sd] = k1v;
      *(bf16x8*)&Vn[dt * 72 + kc] = v0v;
      *(bf16x8*)&Vn[dt * 72 + 32 + kc] = v1v;
    }
    // prefetch tile it+2 (clamped; redundant loads on tail are harmless)
    {
      const int nxt = (it + 2 < 32) ? (it + 2) * 64 : 31 * 64;
      k0v = *(const bf16x8*)&Kb[(size_t)(nxt + skv) * DH + sd];
      k1v = *(const bf16x8*)&Kb[(size_t)(nxt + 32 + skv) * DH + sd];
      v0v = *(const bf16x8*)&Vb[(size_t)dt * SEQ + nxt + kc];
      v1v = *(const bf16x8*)&Vb[(size_t)dt * SEQ + nxt + 32 + kc];
    }

    // ---- shared fragments, read ONCE, reused by both q-groups ----
    bf16x8 ka[4][2], vb[2][4];
#pragma unroll
    for (int t = 0; t < 4; ++t) {
      ka[t][0] = *(const bf16x8*)&Kc[(16 * t + ln) * 72 + 8 * g];
      ka[t][1] = *(const bf16x8*)&Kc[(16 * t + ln) * 72 + 32 + 8 * g];
    }
#pragma unroll
    for (int c = 0; c < 2; ++c)
#pragma unroll
      for (int t = 0; t < 4; ++t)
        vb[c][t] = *(const bf16x8*)&Vc[(16 * t + ln) * 72 + 32 * c + 8 * g];

    // ================= group A (q = qbase + ln) =================
    {
      f32x4 s0 = (f32x4){0.f, 0.f, 0.f, 0.f};
      f32x4 s1 = s0, s2 = s0, s3 = s0;
      __builtin_amdgcn_s_setprio(1);
      s0 = __builtin_amdgcn_mfma_f32_16x16x32_bf16(ka[0][0], qfA0, s0, 0, 0, 0);
      s1 = __builtin_amdgcn_mfma_f32_16x16x32_bf16(ka[1][0], qfA0, s1, 0, 0, 0);
      s2 = __builtin_amdgcn_mfma_f32_16x16x32_bf16(ka[2][0], qfA0, s2, 0, 0, 0);
      s3 = __builtin_amdgcn_mfma_f32_16x16x32_bf16(ka[3][0], qfA0, s3, 0, 0, 0);
      s0 = __builtin_amdgcn_mfma_f32_16x16x32_bf16(ka[0][1], qfA1, s0, 0, 0, 0);
      s1 = __builtin_amdgcn_mfma_f32_16x16x32_bf16(ka[1][1], qfA1, s1, 0, 0, 0);
      s2 = __builtin_amdgcn_mfma_f32_16x16x32_bf16(ka[2][1], qfA1, s2, 0, 0, 0);
      s3 = __builtin_amdgcn_mfma_f32_16x16x32_bf16(ka[3][1], qfA1, s3, 0, 0, 0);
      __builtin_amdgcn_s_setprio(0);

      float p0[4], p1[4], p2[4], p3[4];
#pragma unroll
      for (int r = 0; r < 4; ++r) {
        p0[r] = fast_exp2(s0[r]);
        p1[r] = fast_exp2(s1[r]);
        p2[r] = fast_exp2(s2[r]);
        p3[r] = fast_exp2(s3[r]);
      }

      unsigned a0 = cvt_pk_bf16(p0[0], p0[1]);
      unsigned a2 = cvt_pk_bf16(p1[0], p1[1]);
      unsigned a1 = cvt_pk_bf16(p0[2], p0[3]);
      unsigned a3 = cvt_pk_bf16(p1[2], p1[3]);
      permswap32(a0, a2);
      permswap32(a1, a3);
      unsigned b0 = cvt_pk_bf16(p2[0], p2[1]);
      unsigned b2 = cvt_pk_bf16(p3[0], p3[1]);
      unsigned b1 = cvt_pk_bf16(p2[2], p2[3]);
      unsigned b3 = cvt_pk_bf16(p3[2], p3[3]);
      permswap32(b0, b2);
      permswap32(b1, b3);
      union { unsigned u[4]; bf16x8 v; } pa0, pa1;
      pa0.u[0] = a0; pa0.u[1] = a1; pa0.u[2] = a2; pa0.u[3] = a3;
      pa1.u[0] = b0; pa1.u[1] = b1; pa1.u[2] = b2; pa1.u[3] = b3;

      __builtin_amdgcn_s_setprio(1);
#pragma unroll
      for (int t = 0; t < 4; ++t) {
        oaccA[t] = __builtin_amdgcn_mfma_f32_16x16x32_bf16(pa0.v, vb[0][t], oaccA[t], 0, 0, 0);
        oaccA[t] = __builtin_amdgcn_mfma_f32_16x16x32_bf16(pa1.v, vb[1][t], oaccA[t], 0, 0, 0);
      }
      // denominator on the matrix pipe: row sums of P (col ln uniform)
      oaccDA = __builtin_amdgcn_mfma_f32_16x16x32_bf16(pa0.v, vones, oaccDA, 0, 0, 0);
      oaccDA = __builtin_amdgcn_mfma_f32_16x16x32_bf16(pa1.v, vones, oaccDA, 0, 0, 0);
      __builtin_amdgcn_s_setprio(0);
    }

    // ================= group B (q = qbase + 16 + ln) =================
    {
      f32x4 s0 = (f32x4){0.f, 0.f, 0.f, 0.f};
      f32x4 s1 = s0, s2 = s0, s3 = s0;
      __builtin_amdgcn_s_setprio(1);
      s0 = __builtin_amdgcn_mfma_f32_16x16x32_bf16(ka[0][0], qfB0, s0, 0, 0, 0);
      s1 = __builtin_amdgcn_mfma_f32_16x16x32_bf16(ka[1][0], qfB0, s1, 0, 0, 0);
      s2 = __builtin_amdgcn_mfma_f32_16x16x32_bf16(ka[2][0], qfB0, s2, 0, 0, 0);
      s3 = __builtin_amdgcn_mfma_f32_16x16x32_bf16(ka[3][0], qfB0, s3, 0, 0, 0);
      s0 = __builtin_amdgcn_mfma_f32_16x16x32_bf16(ka[0][1], qfB1, s0, 0, 0, 0);
      s1 = __builtin_amdgcn_mfma_f32_16x16x32_bf16(ka[1][1], qfB1, s1, 0, 0, 0);
      s2 = __builtin_amdgcn_mfma_f32_16x16x32_bf16(ka[2][1], qfB1, s2, 0, 0, 0);
      s3 = __builtin_amdgcn_mfma_f32_16x16x32_bf16(ka[3][1], qfB1, s3, 0, 0, 0);
      __builtin_amdgcn_s_setprio(0);

      float p0[4], p1[4], p2[4], p3[4];
#pragma unroll
      for (int r = 0; r < 4; ++r) {
        p0[r] = fast_exp2(s0[r]);
        p1[r] = fast_exp2(s1[r]);
        p2[r] = fast_exp2(s2[r]);
        p3[r] = fast_exp2(s3[r]);
      }

      unsigned a0 = cvt_pk_bf16(p0[0], p0[1]);
      unsigned a2 = cvt_pk_bf16(p1[0], p1[1]);
      unsigned a1 = cvt_pk_bf16(p0[2], p0[3]);
      unsigned a3 = cvt_pk_bf16(p1[2], p1[3]);
      permswap32(a0, a2);
      permswap32(a1, a3);
      unsigned b0 = cvt_pk_bf16(p2[0], p2[1]);
      unsigned b2 = cvt_pk_bf16(p3[0], p3[1]);
      unsigned b1 = cvt_pk_bf16(p2[2], p2[3]);
      unsigned b3 = cvt_pk_bf16(p3[2], p3[3]);
      permswap32(b0, b2);
      permswap32(b1, b3);
      union { unsigned u[4]; bf16x8 v; } pa0, pa1;
      pa0.u[0] = a0; pa0.u[1] = a1; pa0.u[2] = a2; pa0.u[3] = a3;
      pa1.u[0] = b0; pa1.u[1] = b1; pa1.u[2] = b2; pa1.u[3] = b3;

      __builtin_amdgcn_s_setprio(1);
#pragma unroll
      for (int t = 0; t < 4; ++t) {
        oaccB[t] = __builtin_amdgcn_mfma_f32_16x16x32_bf16(pa0.v, vb[0][t], oaccB[t], 0, 0, 0);
        oaccB[t] = __builtin_amdgcn_mfma_f32_16x16x32_bf16(pa1.v, vb[1][t], oaccB[t], 0, 0, 0);
      }
      oaccDB = __builtin_amdgcn_mfma_f32_16x16x32_bf16(pa0.v, vones, oaccDB, 0, 0, 0);
      oaccDB = __builtin_amdgcn_mfma_f32_16x16x32_bf16(pa1.v, vones, oaccDB, 0, 0, 0);
      __builtin_amdgcn_s_setprio(0);
    }

    // single barrier per iter: my ds reads (buf cur) + writes (buf cur^1) done
    asm volatile("s_waitcnt lgkmcnt(0)" ::: "memory");
    __builtin_amdgcn_s_barrier();
  }

  // ---- epilogue: denominator lane-local in oaccD[r] (row q=4g+r) ----
  const int b = bh >> 3, h = bh & 7;
#pragma unroll
  for (int r = 0; r < 4; ++r) {
    const float irA = 1.0f / oaccDA[r];
    const float irB = 1.0f / oaccDB[r];
    ushort* opA = O + ((size_t)(b * SEQ) + qbase + 4 * g + r) * EMB + h * 64;
    ushort* opB = O + ((size_t)(b * SEQ) + qbase + 16 + 4 * g + r) * EMB + h * 64;
#pragma unroll
    for (int t = 0; t < 4; ++t) {
      opA[16 * t + ln] = f2bf(oaccA[t][r] * irA);
      opB[16 * t + ln] = f2bf(oaccB[t][r] * irB);
    }
  }
}

// ---------------------------------------------------------------------------
extern "C" void kernel_launch(void* const* d_in, const int* in_sizes, int n_in,
                              void* d_out, int out_size, void* d_ws, size_t ws_size,
                              hipStream_t stream) {
  const float* q  = (const float*)d_in[0];
  const float* wq = (const float*)d_in[1];
  const float* bq = (const float*)d_in[2];
  const float* wk = (const float*)d_in[3];
  const float* bk = (const float*)d_in[4];
  const float* wv = (const float*)d_in[5];
  const float* bv = (const float*)d_in[6];
  const float* wo = (const float*)d_in[7];
  const float* bo = (const float*)d_in[8];
  float* out = (float*)d_out;

  const size_t XSZ = (size_t)MTOT * INDIM;
  const size_t WSZ = (size_t)EMB * INDIM;
  const size_t QSZ = (size_t)BATCH * NHEADS * SEQ * DH;
  ushort* wsX = (ushort*)d_ws;
  ushort* wsW = wsX + XSZ;
  ushort* wsQ = wsW + 4 * WSZ;
  ushort* wsK = wsQ + QSZ;
  ushort* wsVT = wsK + QSZ;
  ushort* wsA = wsVT + QSZ;   // attn output bf16 [B,N,EMB]

  const dim3 blk(256);

  conv_bf16<<<dim3(XSZ / 8 / 256), blk, 0, stream>>>(q, wsX, XSZ / 8);
  conv_bf16_w4<<<dim3(WSZ / 8 / 256, 4), blk, 0, stream>>>(wq, wk, wv, wo, wsW, WSZ / 8);

  mfma_gemm<0><<<dim3(MTOT / 128, 1536 / 128), blk, 0, stream>>>(
      wsX, wsW, bq, bk, bv, wsQ, wsK, wsVT, nullptr);

  attn_mfma<<<dim3(512), blk, 0, stream>>>(wsQ, wsK, wsVT, wsA);

  mfma_gemm<1><<<dim3(MTOT / 128, EMB / 128), blk, 0, stream>>>(
      wsA, wsW + 3 * WSZ, bo, nullptr, nullptr, nullptr, nullptr, nullptr, out);
}